// Round 1
// baseline (45.326 us; speedup 1.0000x reference)
//
#include <hip/hip_runtime.h>

// QuantizedGroupEmbedding: out[t, d] = weight[idx[t], d] * scales[idx[t], d/128]
// weight: [128000, 2048] int32 (int8-valued), scales: [128000, 16] f32,
// indices: [4, 4096] int (16384 tokens), out: [16384, 2048] f32.
// Memory-bound gather: ~134 MB read + ~134 MB write -> roofline ~43 us @ 6.3 TB/s.

#define DIM 2048
#define GROUPS 16
// group size = 128 elements -> int4 index v covers elements [4v, 4v+4), group = v >> 5

__global__ __launch_bounds__(256) void qemb_gather_dequant(
    const int* __restrict__ weight,
    const float* __restrict__ scales,
    const int* __restrict__ indices,
    float* __restrict__ out,
    int n_tokens)
{
    const int token = blockIdx.x;
    if (token >= n_tokens) return;

    const int row = indices[token];  // block-uniform -> scalar load path
    const int4* __restrict__ wrow =
        reinterpret_cast<const int4*>(weight + (size_t)row * DIM);
    const float* __restrict__ srow = scales + (size_t)row * GROUPS;
    float4* __restrict__ orow =
        reinterpret_cast<float4*>(out + (size_t)token * DIM);

    const int t = threadIdx.x;
    // 2048 elems = 512 int4 chunks; 256 threads -> 2 chunks/thread, coalesced.
    #pragma unroll
    for (int p = 0; p < 2; ++p) {
        const int v = t + p * 256;          // int4 index within the row
        const int4 w = wrow[v];             // 16B coalesced load
        const float s = srow[v >> 5];       // per-group scale (L1/L2 hit)
        float4 o;
        o.x = (float)w.x * s;
        o.y = (float)w.y * s;
        o.z = (float)w.z * s;
        o.w = (float)w.w * s;
        orow[v] = o;                        // 16B coalesced store
    }
}

extern "C" void kernel_launch(void* const* d_in, const int* in_sizes, int n_in,
                              void* d_out, int out_size, void* d_ws, size_t ws_size,
                              hipStream_t stream) {
    const int*   weight  = (const int*)d_in[0];
    const float* scales  = (const float*)d_in[1];
    const int*   indices = (const int*)d_in[2];
    float*       out     = (float*)d_out;

    const int n_tokens = in_sizes[2];  // 4 * 4096 = 16384

    qemb_gather_dequant<<<n_tokens, 256, 0, stream>>>(
        weight, scales, indices, out, n_tokens);
}